// Round 16
// baseline (495.376 us; speedup 1.0000x reference)
//
#include <hip/hip_runtime.h>
#include <math.h>

// ---------------------------------------------------------------------------
// CNN-LSTM video predictor, round 16: ec1 A-operand pre-converted to bf16
// (half read traffic, conversion hoisted out of conv), to_nhwc4 halved,
// pack_whh merged. Rest = round 15 (495us, absmax 1.95e-3).
// ---------------------------------------------------------------------------

typedef float f32x4 __attribute__((ext_vector_type(4)));
typedef short bf16x8 __attribute__((ext_vector_type(8)));

__device__ __forceinline__ float sig_(float x) { return 1.f / (1.f + expf(-x)); }
__device__ __forceinline__ float dot4(float4 a, float4 b) {
    return a.x * b.x + a.y * b.y + a.z * b.z + a.w * b.w;
}
// LSTM column permutation (8 cols/block, 2 j per block, 256 blocks):
// c = b*8 + g*2 + jl  ->  orig gate row g*512 + b*2 + jl
__device__ __forceinline__ int orig_row(int c) {
    return ((c >> 1) & 3) * 512 + (c >> 3) * 2 + (c & 1);
}
__device__ __forceinline__ unsigned short f2bf(float f) {
    unsigned int b = __float_as_uint(f);
    return (unsigned short)((b + 0x7fffu + ((b >> 16) & 1u)) >> 16);
}
__device__ __forceinline__ float bf2f(unsigned short h) {
    return __uint_as_float(((unsigned int)h) << 16);
}
__device__ __forceinline__ float4 bf4_to_f4(uint2 u) {
    float4 r;
    r.x = __uint_as_float((u.x & 0xffffu) << 16);
    r.y = __uint_as_float(u.x & 0xffff0000u);
    r.z = __uint_as_float((u.y & 0xffffu) << 16);
    r.w = __uint_as_float(u.y & 0xffff0000u);
    return r;
}

// =================== MFMA conv / convT (A bf16, W bf16) =====================
// SRCF32: 0 = bf16 NHWC (CIP>=32 tap-outer path), 2 = bf16 NHWC4 (CIP==4,
// fragment spans 2 taps x 4 ch).
template<int CIP, int HI, int WI, int CO, int MREP, int WM, int WN, int MODE, int SRCF32>
__global__ __launch_bounds__(64 * WM * WN)
void conv_mfma(const unsigned short* __restrict__ Ahi,
               const unsigned short* __restrict__ WB, const float* __restrict__ bias,
               unsigned short* __restrict__ Yhi) {
    constexpr int K    = CIP * (MODE ? 4 : 16);
    constexpr int K32  = K / 32;
    constexpr int NI   = 2 * MREP;
    constexpr int TAPS = MODE ? 4 : 16;
    constexpr int CC   = (CIP >= 32) ? CIP / 32 : 1;
    constexpr int HO   = MODE ? HI * 2 : HI / 2;
    constexpr int WO   = MODE ? WI * 2 : WI / 2;
    constexpr int SH   = MODE ? HI : HI / 2;
    constexpr int SW   = MODE ? WI : WI / 2;
    constexpr int HWS  = SH * SW;
    constexpr int MT   = (256 * HWS) / (32 * MREP * WM);
    constexpr int NT   = CO / (32 * WN);
    constexpr int PLANE = CO * K;

    int bid = blockIdx.x;
    int mt = bid % MT; bid /= MT;
    int nt = bid % NT; int par = bid / NT;
    int p = par >> 1, q = par & 1;

    int tid = threadIdx.x;
    int lane = tid & 63, wid = tid >> 6;
    int wm = wid % WM, wn = wid / WM;
    int mbase = mt * (32 * MREP * WM) + wm * (32 * MREP);
    int nbase = nt * (32 * WN) + wn * 32;
    int lm = lane & 15, lg = lane >> 4;

    int ani[NI], asy[NI], asx[NI];
#pragma unroll
    for (int i = 0; i < NI; ++i) {
        int m = mbase + 16 * i + lm;
        ani[i] = m / HWS; int r = m % HWS; asy[i] = r / SW; asx[i] = r % SW;
    }

    f32x4 acc[NI][2];
#pragma unroll
    for (int i = 0; i < NI; ++i)
#pragma unroll
        for (int j = 0; j < 2; ++j)
#pragma unroll
            for (int e = 0; e < 4; ++e) acc[i][j][e] = 0.f;

    const unsigned short* WBp = WB + (long)par * 2 * PLANE;

    if constexpr (SRCF32 == 2) {
        // CIP==4 bf16 NHWC4: each 8-elem fragment = taps t0,t0+1 x 4 ch
        for (int kb = 0; kb < K; kb += 32) {
            int k0 = kb + lg * 8;
            int t0 = k0 >> 2;
            bf16x8 ah[NI];
#pragma unroll
            for (int i = 0; i < NI; ++i) {
                uint2 u[2];
#pragma unroll
                for (int h = 0; h < 2; ++h) {
                    int tap = t0 + h;
                    int ih = 2 * asy[i] + (tap >> 2) - 1;
                    int iw = 2 * asx[i] + (tap & 3) - 1;
                    int ihc = min(max(ih, 0), HI - 1);
                    int iwc = min(max(iw, 0), WI - 1);
                    unsigned mk = ((unsigned)ih < (unsigned)HI && (unsigned)iw < (unsigned)WI)
                                  ? 0xffffffffu : 0u;
                    uint2 t = *(const uint2*)(Ahi + (((long)ani[i] * HI + ihc) * WI + iwc) * 4);
                    t.x &= mk; t.y &= mk;
                    u[h] = t;
                }
                uint4 uu = {u[0].x, u[0].y, u[1].x, u[1].y};
                ah[i] = *(bf16x8*)&uu;
            }
            bf16x8 bh[2];
#pragma unroll
            for (int j = 0; j < 2; ++j) {
                long bidx = ((long)((nbase >> 4) + j) * K32 + (kb >> 5)) * 512 + lane * 8;
                bh[j] = *(const bf16x8*)(WBp + bidx);
            }
#pragma unroll
            for (int i = 0; i < NI; ++i)
#pragma unroll
                for (int j = 0; j < 2; ++j)
                    acc[i][j] = __builtin_amdgcn_mfma_f32_16x16x32_bf16(ah[i], bh[j], acc[i][j], 0, 0, 0);
        }
    } else {
        long abase[NI]; unsigned vmask[NI];
#pragma unroll
        for (int i = 0; i < NI; ++i) {
            abase[i] = (long)ani[i] * HI * WI * CIP;
            unsigned vm = 0;
#pragma unroll
            for (int t = 0; t < TAPS; ++t) {
                int iy, ix;
                if constexpr (MODE == 0) {
                    iy = 2 * asy[i] + (t >> 2) - 1; ix = 2 * asx[i] + (t & 3) - 1;
                } else {
                    iy = asy[i] + p + (t >> 1) - 1; ix = asx[i] + q + (t & 1) - 1;
                }
                if (iy >= 0 && iy < HI && ix >= 0 && ix < WI) vm |= (1u << t);
            }
            vmask[i] = vm;
        }
#pragma unroll 2
        for (int tap = 0; tap < TAPS; ++tap) {
            int dy, dx;
            if constexpr (MODE == 0) { dy = (tap >> 2) - 1; dx = (tap & 3) - 1; }
            else { dy = p + (tap >> 1) - 1; dx = q + (tap & 1) - 1; }
            long roff[NI]; unsigned msk[NI];
#pragma unroll
            for (int i = 0; i < NI; ++i) {
                int iy = (MODE == 0 ? 2 * asy[i] : asy[i]) + dy;
                int ix = (MODE == 0 ? 2 * asx[i] : asx[i]) + dx;
                int iyc = min(max(iy, 0), HI - 1);
                int ixc = min(max(ix, 0), WI - 1);
                roff[i] = abase[i] + ((long)iyc * WI + ixc) * CIP + lg * 8;
                msk[i] = ((vmask[i] >> tap) & 1u) ? 0xffffffffu : 0u;
            }
#pragma unroll
            for (int cc = 0; cc < CC; ++cc) {
                int kb32 = tap * CC + cc;
                bf16x8 ah[NI];
#pragma unroll
                for (int i = 0; i < NI; ++i) {
                    uint4 u = *(const uint4*)(Ahi + roff[i] + cc * 32);
                    u.x &= msk[i]; u.y &= msk[i]; u.z &= msk[i]; u.w &= msk[i];
                    ah[i] = *(bf16x8*)&u;
                }
                bf16x8 bh[2];
#pragma unroll
                for (int j = 0; j < 2; ++j) {
                    long bidx = ((long)((nbase >> 4) + j) * K32 + kb32) * 512 + lane * 8;
                    bh[j] = *(const bf16x8*)(WBp + bidx);
                }
#pragma unroll
                for (int i = 0; i < NI; ++i)
#pragma unroll
                    for (int j = 0; j < 2; ++j)
                        acc[i][j] = __builtin_amdgcn_mfma_f32_16x16x32_bf16(ah[i], bh[j], acc[i][j], 0, 0, 0);
            }
        }
    }

#pragma unroll
    for (int i = 0; i < NI; ++i)
#pragma unroll
        for (int j = 0; j < 2; ++j)
#pragma unroll
            for (int r = 0; r < 4; ++r) {
                int m = mbase + 16 * i + lg * 4 + r;
                int co = nbase + 16 * j + lm;
                float v = fmaxf(acc[i][j][r] + bias[co], 0.f);
                long off;
                if constexpr (MODE == 0) {
                    off = (long)m * CO + co;
                } else {
                    int ni = m / HWS; int rm = m % HWS;
                    int oy = 2 * (rm / SW) + p, ox = 2 * (rm % SW) + q;
                    off = (((long)ni * HO + oy) * WO + ox) * CO + co;
                }
                Yhi[off] = f2bf(v);
            }
}

// ====== dt4: LDS-tiled (bf16 LDS), 4-row stripes, CO=3, sigmoid, NCHW =======
__global__ __launch_bounds__(128)
void dt4_tiled(const unsigned short* __restrict__ Xh,
               const float4* __restrict__ Wd, const float* __restrict__ bias,
               float* __restrict__ out) {
    __shared__ uint2 xt[8 * 205];
    int bid = blockIdx.x;
    int n = bid >> 3, yg = bid & 7;
    int y0 = yg * 4;
    int tid = threadIdx.x;
    long nb = (long)n * 32768;
    for (int j = tid; j < 1632; j += 128) {
        int c4 = j & 7; int pos = j >> 3;
        int r = pos / 34, cc = pos % 34;
        int ih = y0 - 1 + r, iw = cc - 1;
        uint2 u = {0u, 0u};
        if ((unsigned)ih < 32u && (unsigned)iw < 32u)
            u = *(const uint2*)(Xh + nb + ((long)ih * 32 + iw) * 32 + c4 * 4);
        xt[c4 * 205 + pos] = u;
    }
    __syncthreads();
    int ly = tid >> 5, lx = tid & 31;
    float acc[3][4];
#pragma unroll
    for (int j = 0; j < 3; ++j) {
        float b = bias[j];
#pragma unroll
        for (int par = 0; par < 4; ++par) acc[j][par] = b;
    }
#pragma unroll
    for (int ci4 = 0; ci4 < 8; ++ci4) {
        float4 xv[9];
        int base = ci4 * 205 + ly * 34 + lx;
#pragma unroll
        for (int r = 0; r < 3; ++r)
#pragma unroll
            for (int c = 0; c < 3; ++c)
                xv[r * 3 + c] = bf4_to_f4(xt[base + r * 34 + c]);
        const float4* wp = Wd + ci4 * 48;
#pragma unroll
        for (int j = 0; j < 3; ++j)
#pragma unroll
            for (int par = 0; par < 4; ++par) {
                int p = par >> 1, q = par & 1;
#pragma unroll
                for (int t4 = 0; t4 < 4; ++t4) {
                    int dh = t4 >> 1, dw = t4 & 1;
                    acc[j][par] += dot4(xv[(p + dh) * 3 + (q + dw)],
                                        wp[(j * 4 + par) * 4 + t4]);
                }
            }
    }
    int yy = y0 + ly, xx = lx;
#pragma unroll
    for (int j = 0; j < 3; ++j)
#pragma unroll
        for (int p = 0; p < 2; ++p) {
            float2 v;
            v.x = sig_(acc[j][p * 2 + 0]);
            v.y = sig_(acc[j][p * 2 + 1]);
            *(float2*)(out + (((long)n * 3 + j) * 64 + 2 * yy + p) * 64 + 2 * xx) = v;
        }
}

// ========================= weight / layout prep =============================
__global__ void prep_packs(const float* __restrict__ ec3_w, const float* __restrict__ ec4_w,
                           const float* __restrict__ dt1_w, const float* __restrict__ dt2_w,
                           unsigned short* __restrict__ WBe3, unsigned short* __restrict__ WBe4,
                           unsigned short* __restrict__ WBd1, unsigned short* __restrict__ WBd2) {
    int idx = blockIdx.x * 256 + threadIdx.x;
    if (idx < 131072) {  // ec3 conv: CI=64 CO=128 K=1024
        int li = idx;
        int j = li & 7, lane = (li >> 3) & 63;
        int kb = (li >> 9) & 31, nt = li >> 14;
        int k = kb * 32 + (lane >> 4) * 8 + j;
        int tap = k >> 6, ci = k & 63;
        int co = nt * 16 + (lane & 15);
        float f = ec3_w[((long)co * 64 + ci) * 16 + tap];
        WBe3[li] = f2bf(f);
    } else if (idx < 655360) {  // ec4 conv: CI=128 CO=256 K=2048
        int li = idx - 131072;
        int j = li & 7, lane = (li >> 3) & 63;
        int kb = (li >> 9) & 63, nt = li >> 15;
        int k = kb * 32 + (lane >> 4) * 8 + j;
        int tap = k >> 7, ci = k & 127;
        int co = nt * 16 + (lane & 15);
        float f = ec4_w[((long)co * 128 + ci) * 16 + tap];
        WBe4[li] = f2bf(f);
    } else if (idx < 1179648) {  // dt1 convt: CI=256 CO=128 Kp=1024
        int li = idx - 655360;
        int par = li >> 17; int rem = li & 131071;
        int j = rem & 7, lane = (rem >> 3) & 63;
        int kb = (rem >> 9) & 31, nt = rem >> 14;
        int k = kb * 32 + (lane >> 4) * 8 + j;
        int t4 = k >> 8, ci = k & 255;
        int p = par >> 1, q = par & 1, dh = t4 >> 1, dw = t4 & 1;
        int tap = (p + 2 * dh) * 4 + (q + 2 * dw);
        int co = nt * 16 + (lane & 15);
        float f = dt1_w[((long)co * 256 + ci) * 16 + tap];
        WBd1[(long)par * 262144 + rem] = f2bf(f);
    } else if (idx < 1310720) {  // dt2 convt: CI=128 CO=64 Kp=512
        int li = idx - 1179648;
        int par = li >> 15; int rem = li & 32767;
        int j = rem & 7, lane = (rem >> 3) & 63;
        int kb = (rem >> 9) & 15, nt = rem >> 13;
        int k = kb * 32 + (lane >> 4) * 8 + j;
        int t4 = k >> 7, ci = k & 127;
        int p = par >> 1, q = par & 1, dh = t4 >> 1, dw = t4 & 1;
        int tap = (p + 2 * dh) * 4 + (q + 2 * dw);
        int co = nt * 16 + (lane & 15);
        float f = dt2_w[((long)co * 128 + ci) * 16 + tap];
        WBd2[(long)par * 65536 + rem] = f2bf(f);
    }
}

__global__ void prep_tail(const float* __restrict__ ec1_w, const float* __restrict__ ec2_w,
                          const float* __restrict__ dt3_w, const float* __restrict__ dt4_w,
                          unsigned short* __restrict__ WBe1, unsigned short* __restrict__ WBe2,
                          unsigned short* __restrict__ WBd3, float4* __restrict__ WTd4) {
    int idx = blockIdx.x * 256 + threadIdx.x;
    if (idx < 2048) {
        int li = idx;
        int j = li & 7, lane = (li >> 3) & 63;
        int kb = (li >> 9) & 1, nt = li / 1024;
        int k = kb * 32 + (lane >> 4) * 8 + j;
        int tap = k >> 2, ci = k & 3;
        int co = nt * 16 + (lane & 15);
        float f = (ci < 3) ? ec1_w[((long)co * 3 + ci) * 16 + tap] : 0.f;
        WBe1[li] = f2bf(f);
    } else if (idx < 34816) {
        int li = idx - 2048;
        int j = li & 7, lane = (li >> 3) & 63;
        int kb = (li >> 9) & 15, nt = li / 8192;
        int k = kb * 32 + (lane >> 4) * 8 + j;
        int tap = k >> 5, ci = k & 31;
        int co = nt * 16 + (lane & 15);
        float f = ec2_w[((long)co * 32 + ci) * 16 + tap];
        WBe2[li] = f2bf(f);
    } else if (idx < 67584) {
        int li = idx - 34816;
        int par = li >> 13; int rem = li & 8191;
        int j = rem & 7, lane = (rem >> 3) & 63;
        int kb = (rem >> 9) & 7, nt = rem >> 12;
        int k = kb * 32 + (lane >> 4) * 8 + j;
        int t4 = k >> 6, ci = k & 63;
        int p = par >> 1, q = par & 1, dh = t4 >> 1, dw = t4 & 1;
        int tap = (p + 2 * dh) * 4 + (q + 2 * dw);
        int co = nt * 16 + (lane & 15);
        float f = dt3_w[((long)co * 64 + ci) * 16 + tap];
        WBd3[par * 16384 + rem] = f2bf(f);
    } else if (idx < 67968) {
        int li = idx - 67584;
        int t4 = li & 3, par = (li >> 2) & 3;
        int co = (li >> 4) % 3, ci4 = (li >> 4) / 3;
        int p = par >> 1, q = par & 1, dh = t4 >> 1, dw = t4 & 1;
        int tap = (p + 2 * dh) * 4 + (q + 2 * dw);
        float4 v; float* pv = (float*)&v;
#pragma unroll
        for (int l = 0; l < 4; ++l)
            pv[l] = dt4_w[((long)co * 32 + ci4 * 4 + l) * 16 + tap];
        WTd4[li] = v;
    }
}

__global__ void prep_r1(const float* __restrict__ wih_e, const float* __restrict__ wih_d,
                        const float* __restrict__ fc_w,
                        const float* __restrict__ bih_d, const float* __restrict__ bhh_d,
                        const float* __restrict__ fc_b,
                        const float* __restrict__ fcmu_w, const float* __restrict__ dfc_w,
                        const float* __restrict__ dfc_b,
                        float* __restrict__ WIHP_E, float* __restrict__ WIHP_D,
                        float* __restrict__ FCP, float* __restrict__ BIASDC,
                        float* __restrict__ FCMUP, float* __restrict__ DFCP,
                        float* __restrict__ DFCB) {
    int idx = blockIdx.x * 256 + threadIdx.x;
    if (idx < 262144) {
        int c = idx & 2047, m = idx >> 11;
        WIHP_E[idx] = wih_e[orig_row(c) * 128 + m];
    } else if (idx < 524288) {
        int li = idx - 262144;
        int c = li & 2047, m = li >> 11;
        WIHP_D[li] = wih_d[orig_row(c) * 128 + m];
    } else if (idx < 589824) {
        int li = idx - 524288;
        int r = li & 127, c = li >> 7;
        FCP[li] = fc_w[(long)r * 512 + c];
    } else if (idx < 591872) {
        int c = idx - 589824;
        int orow = orig_row(c);
        float s = bih_d[orow] + bhh_d[orow];
        for (int m = 0; m < 128; ++m) s += fc_b[m] * wih_d[orow * 128 + m];
        BIASDC[c] = s;
    } else if (idx < 1116160) {
        int li = idx - 591872;
        int j = li & 127, k = li >> 7;
        FCMUP[li] = fcmu_w[(long)j * 4096 + (k & 255) * 16 + (k >> 8)];
    } else {
        int li = idx - 1116160;
        int j = li & 4095, m = li >> 12;
        int jc = (j & 255) * 16 + (j >> 8);
        DFCP[li] = dfc_w[(long)jc * 128 + m];
        if (li < 4096) DFCB[li] = dfc_b[(li & 255) * 16 + (li >> 8)];
    }
}

// video NCHW -> bf16 NHWC4
__global__ void to_nhwc4b(const float* __restrict__ v, ushort4* __restrict__ out) {
    int idx = blockIdx.x * 256 + threadIdx.x;  // 1,048,576
    int w = idx & 63, h = (idx >> 6) & 63, n = idx >> 12;
    long base = (long)n * 12288 + h * 64 + w;
    ushort4 o;
    o.x = f2bf(v[base]);
    o.y = f2bf(v[base + 4096]);
    o.z = f2bf(v[base + 8192]);
    o.w = 0;
    out[idx] = o;
}

// both whh packs in one launch (sel by idx)
__global__ void pack_whh2(const float* __restrict__ we, const float* __restrict__ wd,
                          float4* __restrict__ oe, float4* __restrict__ od) {
    int idx = blockIdx.x * 256 + threadIdx.x;  // 524288
    int sel = idx >> 18; int li = idx & 262143;
    int c = li & 2047, k4 = li >> 11;
    const float* w = sel ? wd : we;
    float4* o = sel ? od : oe;
    o[li] = ((const float4*)(w + orig_row(c) * 512))[k4];
}

__global__ __launch_bounds__(256)
void merge_dc(const float* __restrict__ wih_d, const float* __restrict__ fc_w,
              const float* __restrict__ whh_d, float* __restrict__ out) {
    int cb = (blockIdx.x >> 3) * 64, kb = (blockIdx.x & 7) * 64;
    int tid = threadIdx.x;
    int cgl = (tid & 15) * 4, kgl = (tid >> 4) * 4;
    __shared__ float At[64][65];
    __shared__ float Bt[64][65];
    float acc[4][4] = {};
    for (int mc = 0; mc < 128; mc += 64) {
        __syncthreads();
        for (int i = tid; i < 4096; i += 256) {
            int cl = i >> 6, m = i & 63;
            At[cl][m] = wih_d[orig_row(cb + cl) * 128 + mc + m];
            Bt[cl][m] = fc_w[(mc + cl) * 512 + kb + m];
        }
        __syncthreads();
        for (int m = 0; m < 64; ++m) {
            float a[4], b[4];
#pragma unroll
            for (int i = 0; i < 4; ++i) { a[i] = At[cgl + i][m]; b[i] = Bt[m][kgl + i]; }
#pragma unroll
            for (int i = 0; i < 4; ++i)
#pragma unroll
                for (int j = 0; j < 4; ++j) acc[i][j] += a[i] * b[j];
        }
    }
    for (int i = 0; i < 4; ++i) {
        int c = cb + cgl + i; int orow = orig_row(c);
        for (int j = 0; j < 4; ++j) {
            int k = kb + kgl + j;
            out[((k >> 2) * 2048 + c) * 4 + (k & 3)] = acc[i][j] + whh_d[orow * 512 + k];
        }
    }
}

// ============================ LSTM / FC path ================================
__global__ __launch_bounds__(512)
void gx2_kernel(const float* __restrict__ Z,
                const float* __restrict__ wE, const float* __restrict__ biE,
                const float* __restrict__ bhE,
                const float* __restrict__ wD, const float* __restrict__ biD,
                const float* __restrict__ bhD,
                float* __restrict__ gxe, float* __restrict__ gxd0) {
    __shared__ float zl[2048];
    int bid = blockIdx.x, tid = threadIdx.x;
    if (bid < 128) {
        int rg = bid >> 2, cch = bid & 3;   // 32 groups of 8 rows
        for (int i = tid; i < 1024; i += 512)
            zl[i] = Z[(long)(rg * 8 + (i >> 7)) * 128 + (i & 127)];
        __syncthreads();
        int c = cch * 512 + tid;
        int orow = orig_row(c);
        float bsum = biE[orow] + bhE[orow];
        float acc[8];
#pragma unroll
        for (int r = 0; r < 8; ++r) acc[r] = bsum;
        for (int m = 0; m < 128; ++m) {
            float wv = wE[m * 2048 + c];
#pragma unroll
            for (int r = 0; r < 8; ++r) acc[r] += zl[r * 128 + m] * wv;
        }
        for (int r = 0; r < 8; ++r) gxe[(long)(rg * 8 + r) * 2048 + c] = acc[r];
    } else {
        int cch = bid - 128;
        for (int i = tid; i < 2048; i += 512)
            zl[i] = Z[(long)((i >> 7) * 16 + 15) * 128 + (i & 127)];
        __syncthreads();
        int c = cch * 512 + tid;
        int orow = orig_row(c);
        float bsum = biD[orow] + bhD[orow];
        float acc[16];
#pragma unroll
        for (int r = 0; r < 16; ++r) acc[r] = bsum;
        for (int m = 0; m < 128; ++m) {
            float wv = wD[m * 2048 + c];
#pragma unroll
            for (int r = 0; r < 16; ++r) acc[r] += zl[r * 128 + m] * wv;
        }
        for (int r = 0; r < 16; ++r) gxd0[(long)r * 2048 + c] = acc[r];
    }
}

// one LSTM step: 256 blocks x 256 threads; block owns 8 cols (2 j x 4 gates),
// 2-way k-split per column, LDS pair-reduce.
__global__ __launch_bounds__(256)
void lstm_step(const float4* __restrict__ wh4, const float* __restrict__ gadd,
               int gstride, const float* __restrict__ h_in, float* __restrict__ h_out,
               float* __restrict__ cst, float* __restrict__ hall) {
    __shared__ float hs[8192];
    __shared__ float gp[2][16][8];
    int tid = threadIdx.x;
    float4* hs4 = (float4*)hs;
    const float4* hi4 = (const float4*)h_in;
#pragma unroll
    for (int i = 0; i < 8; ++i) hs4[tid + 256 * i] = hi4[tid + 256 * i];
    __syncthreads();
    int col = tid & 7, n = (tid >> 3) & 15, kh = tid >> 7;
    int cg = blockIdx.x * 8 + col;
    const float4* wp = wh4 + cg;
    const float4* hv = (const float4*)(hs + n * 512);
    float acc = 0.f;
    int k0 = kh * 64;
#pragma unroll 8
    for (int k4 = k0; k4 < k0 + 64; ++k4) {
        float4 wv = wp[(long)k4 * 2048];
        float4 h4 = hv[k4];
        acc += wv.x * h4.x + wv.y * h4.y + wv.z * h4.z + wv.w * h4.w;
    }
    gp[kh][n][col] = acc;
    __syncthreads();
    if (tid < 128) {
        int cc = tid & 7, nn = tid >> 3;
        gp[0][nn][cc] = gp[0][nn][cc] + gp[1][nn][cc]
                      + gadd[nn * gstride + blockIdx.x * 8 + cc];
    }
    __syncthreads();
    if (tid < 32) {
        int c2 = tid & 1, n2 = tid >> 1;
        float gi = sig_(gp[0][n2][c2]);
        float gf = sig_(gp[0][n2][c2 + 2]);
        float gg = tanhf(gp[0][n2][c2 + 4]);
        float go = sig_(gp[0][n2][c2 + 6]);
        int j = blockIdx.x * 2 + c2;
        int idx = n2 * 512 + j;
        float cv = gf * cst[idx] + gi * gg;
        cst[idx] = cv;
        float hvv = go * tanhf(cv);
        h_out[idx] = hvv;
        if (hall) hall[idx] = hvv;
    }
}

// fcmu partials: 256 blocks = 16 row-groups x 16 k-slices (256 K each)
__global__ __launch_bounds__(512)
void fcmu_part(const unsigned short* __restrict__ xh,
               const float* __restrict__ wP, float* __restrict__ part) {
    int rg = blockIdx.x >> 4, ks = blockIdx.x & 15;
    int tid = threadIdx.x;
    __shared__ float xls[16 * 256];
    for (int i = tid; i < 4096; i += 512) {
        long gi = (long)(rg * 16 + (i >> 8)) * 4096 + ks * 256 + (i & 255);
        xls[i] = bf2f(xh[gi]);
    }
    __syncthreads();
    int j = tid & 127, rq = tid >> 7;
    float acc[4] = {0, 0, 0, 0};
    for (int k = 0; k < 256; ++k) {
        float wv = wP[(ks * 256 + k) * 128 + j];
#pragma unroll
        for (int i = 0; i < 4; ++i) acc[i] += xls[(rq + 4 * i) * 256 + k] * wv;
    }
    for (int i = 0; i < 4; ++i)
        part[((long)ks * 256 + rg * 16 + rq + 4 * i) * 128 + j] = acc[i];
}

__global__ void fcmu_red(const float* __restrict__ part, const float* __restrict__ b,
                         float* __restrict__ z) {
    int idx = blockIdx.x * 256 + threadIdx.x;  // 32768
    float s = b[idx & 127];
    for (int k = 0; k < 16; ++k) s += part[k * 32768 + idx];
    z[idx] = s;
}

// zs: 64 blocks = 16 t x 4 n-quads; thread = (j, n-local), 1 output
__global__ __launch_bounds__(512)
void zs_k(const float* __restrict__ hall, const float* __restrict__ fcP,
          const float* __restrict__ fcb, float* __restrict__ zs) {
    int t = blockIdx.x >> 2, nq = blockIdx.x & 3;
    int tid = threadIdx.x;
    __shared__ float hs[4 * 512];
    const float* h = hall + (long)t * 8192 + nq * 2048;
    for (int i = tid; i < 2048; i += 512) hs[i] = h[i];
    __syncthreads();
    int j = tid & 127, nl = tid >> 7;
    float a0 = 0.f, a1 = 0.f, a2 = 0.f, a3 = 0.f;
    const float* hr = hs + nl * 512;
    for (int k = 0; k < 512; k += 4) {
        a0 += hr[k] * fcP[k * 128 + j];
        a1 += hr[k + 1] * fcP[(k + 1) * 128 + j];
        a2 += hr[k + 2] * fcP[(k + 2) * 128 + j];
        a3 += hr[k + 3] * fcP[(k + 3) * 128 + j];
    }
    int n = nq * 4 + nl;
    zs[((long)n * 16 + t) * 128 + j] = (a0 + a1) + (a2 + a3) + fcb[j];
}

// dfc: 1024 blocks = 64 row-quads x 16 j-chunks (256 j each)
__global__ __launch_bounds__(256)
void dfc_k(const float* __restrict__ zs, const float* __restrict__ dP,
           const float* __restrict__ db, unsigned short* __restrict__ outh) {
    int rg = blockIdx.x >> 4, jc = blockIdx.x & 15;
    int tid = threadIdx.x;
    __shared__ float zl[512];
    for (int i = tid; i < 512; i += 256) zl[i] = zs[(long)rg * 512 + i];
    __syncthreads();
    int j = jc * 256 + tid;
    float acc[4] = {0.f, 0.f, 0.f, 0.f};
    for (int m = 0; m < 128; ++m) {
        float wv = dP[(long)m * 4096 + j];
#pragma unroll
        for (int r = 0; r < 4; ++r) acc[r] += zl[r * 128 + m] * wv;
    }
    float bv = db[j];
    for (int r = 0; r < 4; ++r) {
        float v = fmaxf(acc[r] + bv, 0.f);
        outh[(long)(rg * 4 + r) * 4096 + j] = f2bf(v);
    }
}

extern "C" void kernel_launch(void* const* d_in, const int* in_sizes, int n_in,
                              void* d_out, int out_size, void* d_ws, size_t ws_size,
                              hipStream_t stream) {
    (void)in_sizes; (void)n_in; (void)out_size; (void)ws_size;
    const float* video  = (const float*)d_in[0];
    const float* ec1_w  = (const float*)d_in[2];  const float* ec1_b = (const float*)d_in[3];
    const float* ec2_w  = (const float*)d_in[4];  const float* ec2_b = (const float*)d_in[5];
    const float* ec3_w  = (const float*)d_in[6];  const float* ec3_b = (const float*)d_in[7];
    const float* ec4_w  = (const float*)d_in[8];  const float* ec4_b = (const float*)d_in[9];
    const float* fcmu_w = (const float*)d_in[10]; const float* fcmu_b = (const float*)d_in[11];
    const float* dfc_w  = (const float*)d_in[12]; const float* dfc_b = (const float*)d_in[13];
    const float* dt1_w  = (const float*)d_in[14]; const float* dt1_b = (const float*)d_in[15];
    const float* dt2_w  = (const float*)d_in[16]; const float* dt2_b = (const float*)d_in[17];
    const float* dt3_w  = (const float*)d_in[18]; const float* dt3_b = (const float*)d_in[19];
    const float* dt4_w  = (const float*)d_in[20]; const float* dt4_b = (const float*)d_in[21];
    const float* wih_e  = (const float*)d_in[22]; const float* whh_e = (const float*)d_in[23];
    const float* bih_e  = (const float*)d_in[24]; const float* bhh_e = (const float*)d_in[25];
    const float* wih_d  = (const float*)d_in[26]; const float* whh_d = (const float*)d_in[27];
    const float* bih_d  = (const float*)d_in[28]; const float* bhh_d = (const float*)d_in[29];
    const float* fc_w   = (const float*)d_in[30]; const float* fc_b  = (const float*)d_in[31];

    char* wsb = (char*)d_ws;
    unsigned short* B1h = (unsigned short*)wsb;              // 8,388,608 e
    unsigned short* X0b = (unsigned short*)(wsb + 33554432); // 4,194,304 e (bf16 NHWC4)
    unsigned short* B2h = (unsigned short*)(wsb + 33554432); // 4,194,304 e
    unsigned short* B3h = (unsigned short*)(wsb + 50331648); // 2,097,152 e
    unsigned short* B4h = (unsigned short*)(wsb + 58720256); // 1,048,576 e
    float* R1f    = (float*)wsb;
    float* WH4_E  = R1f;
    float* WH4_DC = R1f + 1048576;
    float* WIHP_E = R1f + 2097152;
    float* WIHP_D = R1f + 2359296;
    float* GX_E   = R1f + 2621440;
    float* GX_D0  = R1f + 3145728;
    float* BIASDC = R1f + 3178496;
    float* HA     = R1f + 3180544;
    float* HB     = R1f + 3188736;
    float* CB     = R1f + 3196928;
    float* HALL   = R1f + 3205120;
    float* FCMUP  = R1f + 3336192;
    float* FCP    = R1f + 4122624;
    float* DFCP   = R1f + 4188160;
    float* DFCB   = R1f + 4712448;
    float* Z      = R1f + 4716544;
    float* ZS     = R1f + 4749312;
    unsigned short* WBe3 = (unsigned short*)(R1f + 4782080);
    unsigned short* WBe4 = (unsigned short*)(R1f + 4913152);
    unsigned short* WBd1 = (unsigned short*)(R1f + 5437440);
    unsigned short* WBd2 = (unsigned short*)(R1f + 5961728);
    float* ZPART  = R1f + 6092800;   // 524,288 (16 k-slices)
    float* WH4_D0 = R1f + 6617088;   // 1,048,576 (decoder step-0 whh pack)
    unsigned short* WBe1 = (unsigned short*)(wsb + 62914560);
    unsigned short* WBe2 = (unsigned short*)(wsb + 62922752);
    unsigned short* WBd3 = (unsigned short*)(wsb + 63053824);
    float*          WTd4 = (float*)(wsb + 63184896);

    // ---- merged tail prep + encoder ec1/ec2 ----
    prep_tail<<<266, 256, 0, stream>>>(ec1_w, ec2_w, dt3_w, dt4_w,
                                       WBe1, WBe2, WBd3, (float4*)WTd4);
    to_nhwc4b<<<4096, 256, 0, stream>>>(video, (ushort4*)X0b);
    conv_mfma<4, 64, 64, 32, 2, 4, 1, 0, 2><<<1024, 256, 0, stream>>>(
        X0b, WBe1, ec1_b, B1h);
    conv_mfma<32, 32, 32, 64, 2, 2, 2, 0, 0><<<512, 256, 0, stream>>>(
        B1h, WBe2, ec2_b, B2h);

    // ---- R1 free: merged preps ----
    prep_r1<<<6408, 256, 0, stream>>>(wih_e, wih_d, fc_w, bih_d, bhh_d, fc_b,
                                      fcmu_w, dfc_w, dfc_b,
                                      WIHP_E, WIHP_D, FCP, BIASDC, FCMUP, DFCP, DFCB);
    prep_packs<<<5120, 256, 0, stream>>>(ec3_w, ec4_w, dt1_w, dt2_w,
                                         WBe3, WBe4, WBd1, WBd2);
    pack_whh2<<<2048, 256, 0, stream>>>(whh_e, whh_d, (float4*)WH4_E, (float4*)WH4_D0);
    merge_dc<<<256, 256, 0, stream>>>(wih_d, fc_w, whh_d, WH4_DC);
    hipMemsetAsync(HA, 0, 3 * 8192 * sizeof(float), stream);

    // ---- encoder ec3/ec4 + fcmu ----
    conv_mfma<64, 16, 16, 128, 1, 2, 2, 0, 0><<<512, 256, 0, stream>>>(
        B2h, WBe3, ec3_b, B3h);
    conv_mfma<128, 8, 8, 256, 1, 1, 2, 0, 0><<<512, 128, 0, stream>>>(
        B3h, WBe4, ec4_b, B4h);
    fcmu_part<<<256, 512, 0, stream>>>(B4h, FCMUP, ZPART);
    fcmu_red<<<128, 256, 0, stream>>>(ZPART, fcmu_b, Z);

    // ---- merged x projections ----
    gx2_kernel<<<132, 512, 0, stream>>>(Z, WIHP_E, bih_e, bhh_e,
                                        WIHP_D, bih_d, bhh_d, GX_E, GX_D0);

    // ---- LSTM chains (per-step launches; coop grid-sync measured 5x slower) ----
    float* hin = HA; float* hout = HB;
    for (int t = 0; t < 16; ++t) {
        lstm_step<<<256, 256, 0, stream>>>((const float4*)WH4_E, GX_E + t * 2048, 32768,
                                           hin, hout, CB, (float*)nullptr);
        float* tmp = hin; hin = hout; hout = tmp;
    }
    lstm_step<<<256, 256, 0, stream>>>((const float4*)WH4_D0, GX_D0, 2048,
                                       hin, hout, CB, HALL);
    { float* tmp = hin; hin = hout; hout = tmp; }
    for (int t = 1; t < 16; ++t) {
        lstm_step<<<256, 256, 0, stream>>>((const float4*)WH4_DC, BIASDC, 0,
                                           hin, hout, CB, HALL + t * 8192);
        float* tmp = hin; hin = hout; hout = tmp;
    }
    zs_k<<<64, 512, 0, stream>>>(HALL, FCP, fc_b, ZS);

    // ---- decoder ----
    dfc_k<<<1024, 256, 0, stream>>>(ZS, DFCP, DFCB, B4h);
    conv_mfma<256, 4, 4, 128, 1, 2, 2, 1, 0><<<512, 256, 0, stream>>>(
        B4h, WBd1, dt1_b, B3h);
    conv_mfma<128, 8, 8, 64, 2, 2, 2, 1, 0><<<512, 256, 0, stream>>>(
        B3h, WBd2, dt2_b, B2h);
    conv_mfma<64, 16, 16, 32, 2, 4, 1, 1, 0><<<1024, 256, 0, stream>>>(
        B2h, WBd3, dt3_b, B1h);
    dt4_tiled<<<2048, 128, 0, stream>>>(B1h, (const float4*)WTd4, dt4_b, (float*)d_out);
}